// Round 11
// baseline (406.493 us; speedup 1.0000x reference)
//
#include <hip/hip_runtime.h>
#include <math.h>

#define NK 21

typedef __attribute__((ext_vector_type(8))) _Float16 half8;
typedef __attribute__((ext_vector_type(4))) float floatx4;
typedef __attribute__((ext_vector_type(2))) float f32x2;

__device__ __forceinline__ float ex2(float x) { return __builtin_amdgcn_exp2f(x); }
__device__ __forceinline__ float rsq(float x) { return __builtin_amdgcn_rsqf(x); }
__device__ __forceinline__ float lg2(float x) { return __builtin_amdgcn_logf(x); }
__device__ __forceinline__ f32x2 bc2(float s) { f32x2 r = {s, s}; return r; }

// ---------------- normalized-f16 embedding table build ----------------
// 8 threads/row, 32 rows/block.
__global__ __launch_bounds__(256) void knrm_norm_table(
    const float* __restrict__ emb, _Float16* __restrict__ tab, int vocab) {
  const int t = threadIdx.x;
  const int row = blockIdx.x * 32 + (t >> 3);
  const int part = t & 7;
  if (row >= vocab) return;
  const float4* src = (const float4*)(emb + (size_t)row * 64 + part * 8);
  const float4 v0 = src[0], v1 = src[1];
  float ss = v0.x*v0.x + v0.y*v0.y + v0.z*v0.z + v0.w*v0.w
           + v1.x*v1.x + v1.y*v1.y + v1.z*v1.z + v1.w*v1.w;
  ss += __shfl_xor(ss, 1);
  ss += __shfl_xor(ss, 2);
  ss += __shfl_xor(ss, 4);
  const float sc = rsq(fmaxf(ss, 1e-24f));
  half8 hv;
  hv[0] = (_Float16)(v0.x * sc); hv[1] = (_Float16)(v0.y * sc);
  hv[2] = (_Float16)(v0.z * sc); hv[3] = (_Float16)(v0.w * sc);
  hv[4] = (_Float16)(v1.x * sc); hv[5] = (_Float16)(v1.y * sc);
  hv[6] = (_Float16)(v1.z * sc); hv[7] = (_Float16)(v1.w * sc);
  *(half8*)(tab + (size_t)row * 64 + part * 8) = hv;
}

// One block per (batch, pair). 256 threads = 4 waves.
// mm via mfma_f32_16x16x32_f16, swapped operands: D[doc][q], each lane's 4
// c-regs = 4 docs of ONE q-row. Compiler-codegen f32x2 exp-chain (round-9
// form: the explicit v_pk asm variant measured +7% from copies).
// LDS ~16.8 KB (ed chunk = 64 docs, 8 chunks) so all 8 blocks/CU of the
// grid are co-resident -> no 6+2 batch tail. launch_bounds(256,8) caps
// VGPR at 64 (round-9 measured exactly 64).
template <bool PRENORM>
__global__ __launch_bounds__(256, 8) void knrm_main(
    const int* __restrict__ q1i, const int* __restrict__ d1i,
    const int* __restrict__ q2i, const int* __restrict__ d2i,
    const float* __restrict__ emb, const _Float16* __restrict__ tab,
    const float* __restrict__ w1, const float* __restrict__ b1,
    const float* __restrict__ w2, const float* __restrict__ b2,
    const float* __restrict__ w3, const float* __restrict__ b3,
    float* __restrict__ logits, int B)
{
  __shared__ _Float16 s_eq[64 * 64];
  __shared__ _Float16 s_ed[64 * 64];
  __shared__ float s_part[4][NK];
  __shared__ float s_F[NK];

  const int t = threadIdx.x;
  const int b = blockIdx.x;
  const int pair = blockIdx.y;
  const int* __restrict__ qid = pair ? q2i : q1i;
  const int* __restrict__ did = pair ? d2i : d1i;

  // exp(-0.5((x-mu)/sg)^2) = exp2(cf*(x-mu)^2), cf = -0.5*log2(e)/sg^2
  const float cf = -72.13475204444817f;   // sg = 0.1
  const float c1 = 7.213475204444817f;    // -2*cf*0.05
  // A[k] = exp(-0.5*(0.5+k)^2)
  const float A[10] = {
    0.88249690f, 0.32465247f, 0.043936934f, 0.0021874911f, 4.0065260e-5f,
    2.6995838e-7f, 6.6915900e-10f, 6.1022440e-13f, 2.0470720e-16f, 2.5261690e-20f};

  // ---------------- stage eq: 512 slots, 2 slot-writes/thread ----------
  // linear slot lin: row q = lin>>3, k-slot s = (lin&7)^(q&7);
  // swizzled addr(q,s) = q*8 + (s^(q&7)) = lin => write linear in t.
#pragma unroll
  for (int n = 0; n < 2; ++n) {
    const int lin = n * 256 + t;
    const int q = lin >> 3;
    const int s = (lin & 7) ^ (q & 7);
    const int id = qid[b * 64 + q];
    if (PRENORM) {
      *(half8*)&s_eq[lin * 8] = *(const half8*)(tab + (size_t)id * 64 + s * 8);
    } else {
      const float4* src = (const float4*)(emb + (size_t)id * 64 + s * 8);
      const float4 v0 = src[0], v1 = src[1];
      float ss = v0.x*v0.x + v0.y*v0.y + v0.z*v0.z + v0.w*v0.w
               + v1.x*v1.x + v1.y*v1.y + v1.z*v1.z + v1.w*v1.w;
      ss += __shfl_xor(ss, 1);
      ss += __shfl_xor(ss, 2);
      ss += __shfl_xor(ss, 4);
      const float sc = rsq(fmaxf(ss, 1e-24f));
      half8 hv;
      hv[0] = (_Float16)(v0.x * sc); hv[1] = (_Float16)(v0.y * sc);
      hv[2] = (_Float16)(v0.z * sc); hv[3] = (_Float16)(v0.w * sc);
      hv[4] = (_Float16)(v1.x * sc); hv[5] = (_Float16)(v1.y * sc);
      hv[6] = (_Float16)(v1.z * sc); hv[7] = (_Float16)(v1.w * sc);
      *(half8*)&s_eq[lin * 8] = hv;
    }
  }

  const int lane = t & 63;
  const int w  = t >> 6;             // wave id = q-tile
  const int lr = lane & 15;          // q index within tile
  const int lg = lane >> 4;          // k-group / doc-subgroup
  const int qrow = w * 16 + lr;

  f32x2 kacc2[20];
#pragma unroll
  for (int i = 0; i < 20; ++i) kacc2[i] = bc2(0.0f);
  float kacc20 = 0.0f;

  half8 af0, af1;                    // eq fragment (B operand), fixed per lane

  for (int ch = 0; ch < 8; ++ch) {   // 8 chunks of 64 docs
    if (ch) __syncthreads();         // prior chunk's mm reads done
    // -------------- stage ed chunk: 512 slots, 2 slot-writes/thread ----
#pragma unroll
    for (int n = 0; n < 2; ++n) {
      const int lin = n * 256 + t;
      const int d = lin >> 3;
      const int s = (lin & 7) ^ (d & 7);
      const int id = did[b * 512 + ch * 64 + d];
      if (PRENORM) {
        *(half8*)&s_ed[lin * 8] = *(const half8*)(tab + (size_t)id * 64 + s * 8);
      } else {
        const float4* src = (const float4*)(emb + (size_t)id * 64 + s * 8);
        const float4 v0 = src[0], v1 = src[1];
        float ss = v0.x*v0.x + v0.y*v0.y + v0.z*v0.z + v0.w*v0.w
                 + v1.x*v1.x + v1.y*v1.y + v1.z*v1.z + v1.w*v1.w;
        ss += __shfl_xor(ss, 1);
        ss += __shfl_xor(ss, 2);
        ss += __shfl_xor(ss, 4);
        const float sc = rsq(fmaxf(ss, 1e-24f));
        half8 hv;
        hv[0] = (_Float16)(v0.x * sc); hv[1] = (_Float16)(v0.y * sc);
        hv[2] = (_Float16)(v0.z * sc); hv[3] = (_Float16)(v0.w * sc);
        hv[4] = (_Float16)(v1.x * sc); hv[5] = (_Float16)(v1.y * sc);
        hv[6] = (_Float16)(v1.z * sc); hv[7] = (_Float16)(v1.w * sc);
        *(half8*)&s_ed[lin * 8] = hv;
      }
    }
    __syncthreads();

    if (ch == 0) {                    // B-fragments: load once, reuse
      const int q7 = qrow & 7;
      af0 = *(const half8*)&s_eq[(qrow * 8 + ((0 + lg) ^ q7)) * 8];
      af1 = *(const half8*)&s_eq[(qrow * 8 + ((4 + lg) ^ q7)) * 8];
    }

    // -------------- 4 d-tiles: 2 MFMA (A=ed) + packed exp-chain ---------
#pragma unroll
    for (int dt = 0; dt < 4; ++dt) {
      const int drow = dt * 16 + lr;
      const int d7 = drow & 7;
      const half8 b0 = *(const half8*)&s_ed[(drow * 8 + ((0 + lg) ^ d7)) * 8];
      const half8 b1 = *(const half8*)&s_ed[(drow * 8 + ((4 + lg) ^ d7)) * 8];
      floatx4 c = {0.0f, 0.0f, 0.0f, 0.0f};
      c = __builtin_amdgcn_mfma_f32_16x16x32_f16(b0, af0, c, 0, 0, 0);
      c = __builtin_amdgcn_mfma_f32_16x16x32_f16(b1, af1, c, 0, 0, 0);
      // c[r] = mm[doc = ch*64 + dt*16 + 4*lg + r][qrow]; 2 f32x2 pairs
#pragma unroll
      for (int pr = 0; pr < 2; ++pr) {
        const f32x2 x = {c[2 * pr], c[2 * pr + 1]};
        // mu=1.0, sg=0.001: nonzero only for exact token match (ref ~ 1.0)
        kacc20 += (x[0] > 0.99f ? 1.0f : 0.0f) + (x[1] > 0.99f ? 1.0f : 0.0f);
        const f32x2 xx = x * x;
        f32x2 u, gp, gn;
        u[0]  = ex2(cf * xx[0]); u[1]  = ex2(cf * xx[1]);
        const f32x2 ag = bc2(c1) * x;
        gp[0] = ex2(ag[0]);  gp[1] = ex2(ag[1]);
        gn[0] = ex2(-ag[0]); gn[1] = ex2(-ag[1]);
        const f32x2 h = gp * gp, rh = gn * gn;
        f32x2 v = u * gp, vn = u * gn;
#pragma unroll
        for (int k = 0; k < 10; ++k) {
          kacc2[10 + k] += v * bc2(A[k]);   // v_pk_fma_f32
          kacc2[9 - k]  += vn * bc2(A[k]);
          if (k < 9) { v *= h; vn *= rh; }  // v_pk_mul_f32
        }
      }
    }
  }

  // ---------------- reduce: docs (xor16,32) -> log1p -> q (xor1,2,4,8) ----
  float F[NK];
#pragma unroll
  for (int i = 0; i < NK; ++i) {
    float v = (i < 20) ? (kacc2[i][0] + kacc2[i][1]) : kacc20;
    v += __shfl_xor(v, 16);
    v += __shfl_xor(v, 32);                 // per-(q-row) total over 512 docs
    v = 0.6931471805599453f * lg2(1.0f + v);  // log1p
    v += __shfl_xor(v, 1);
    v += __shfl_xor(v, 2);
    v += __shfl_xor(v, 4);
    v += __shfl_xor(v, 8);                  // sum over this wave's 16 q-rows
    F[i] = v;
  }
  if (lane == 0) {
#pragma unroll
    for (int i = 0; i < NK; ++i) s_part[w][i] = F[i];
  }
  __syncthreads();

  if (t < NK)
    s_F[t] = s_part[0][t] + s_part[1][t] + s_part[2][t] + s_part[3][t];
  __syncthreads();

  // tiny MLP 21->10->5->1 on thread 0
  if (t == 0) {
    float h1[10], h2[5];
#pragma unroll
    for (int j = 0; j < 10; ++j) {
      float s = b1[j];
      for (int i = 0; i < NK; ++i) s = fmaf(s_F[i], w1[j * NK + i], s);
      h1[j] = fmaxf(s, 0.0f);
    }
#pragma unroll
    for (int j = 0; j < 5; ++j) {
      float s = b2[j];
#pragma unroll
      for (int i = 0; i < 10; ++i) s = fmaf(h1[i], w2[j * 10 + i], s);
      h2[j] = fmaxf(s, 0.0f);
    }
    float s = b3[0];
#pragma unroll
    for (int j = 0; j < 5; ++j) s = fmaf(h2[j], w3[j], s);
    logits[pair * B + b] = s;
  }
}

__global__ void knrm_finalize(const float* __restrict__ logits,
                              float* __restrict__ out, int B) {
  const int b = blockIdx.x * blockDim.x + threadIdx.x;
  if (b < B) {
    const float d = logits[b] - logits[B + b];
    out[b] = 1.0f / (1.0f + expf(-d));
  }
}

extern "C" void kernel_launch(void* const* d_in, const int* in_sizes, int n_in,
                              void* d_out, int out_size, void* d_ws, size_t ws_size,
                              hipStream_t stream) {
  const int* q1 = (const int*)d_in[0];
  const int* d1 = (const int*)d_in[1];
  const int* q2 = (const int*)d_in[2];
  const int* d2 = (const int*)d_in[3];
  const float* emb = (const float*)d_in[4];
  const float* w1 = (const float*)d_in[5];
  const float* b1 = (const float*)d_in[6];
  const float* w2 = (const float*)d_in[7];
  const float* b2 = (const float*)d_in[8];
  const float* w3 = (const float*)d_in[9];
  const float* b3 = (const float*)d_in[10];

  const int B = in_sizes[0] / 64;
  const int vocab = in_sizes[4] / 64;
  const size_t tab_bytes = (size_t)vocab * 64 * sizeof(_Float16);
  const bool prenorm = ws_size >= tab_bytes + (size_t)2 * B * sizeof(float) + 256;

  dim3 grid(B, 2);
  if (prenorm) {
    _Float16* tab = (_Float16*)d_ws;
    float* logits = (float*)((char*)d_ws + ((tab_bytes + 255) & ~(size_t)255));
    knrm_norm_table<<<(vocab + 31) / 32, 256, 0, stream>>>(emb, tab, vocab);
    knrm_main<true><<<grid, 256, 0, stream>>>(q1, d1, q2, d2, emb, tab,
                                              w1, b1, w2, b2, w3, b3, logits, B);
    knrm_finalize<<<(B + 255) / 256, 256, 0, stream>>>(logits, (float*)d_out, B);
  } else {
    float* logits = (float*)d_ws;
    knrm_main<false><<<grid, 256, 0, stream>>>(q1, d1, q2, d2, emb, nullptr,
                                               w1, b1, w2, b2, w3, b3, logits, B);
    knrm_finalize<<<(B + 255) / 256, 256, 0, stream>>>(logits, (float*)d_out, B);
  }
}

// Round 12
// 239.116 us; speedup vs baseline: 1.7000x; 1.7000x over previous
//
#include <hip/hip_runtime.h>
#include <math.h>

#define NK 21

typedef __attribute__((ext_vector_type(8))) _Float16 half8;
typedef __attribute__((ext_vector_type(4))) float floatx4;
typedef __attribute__((ext_vector_type(2))) float f32x2;

__device__ __forceinline__ float ex2(float x) { return __builtin_amdgcn_exp2f(x); }
__device__ __forceinline__ float rsq(float x) { return __builtin_amdgcn_rsqf(x); }
__device__ __forceinline__ float lg2(float x) { return __builtin_amdgcn_logf(x); }
__device__ __forceinline__ f32x2 bc2(float s) { f32x2 r = {s, s}; return r; }

// ---------------- normalized-f16 embedding table build ----------------
// 8 threads/row, 32 rows/block.
__global__ __launch_bounds__(256) void knrm_norm_table(
    const float* __restrict__ emb, _Float16* __restrict__ tab, int vocab) {
  const int t = threadIdx.x;
  const int row = blockIdx.x * 32 + (t >> 3);
  const int part = t & 7;
  if (row >= vocab) return;
  const float4* src = (const float4*)(emb + (size_t)row * 64 + part * 8);
  const float4 v0 = src[0], v1 = src[1];
  float ss = v0.x*v0.x + v0.y*v0.y + v0.z*v0.z + v0.w*v0.w
           + v1.x*v1.x + v1.y*v1.y + v1.z*v1.z + v1.w*v1.w;
  ss += __shfl_xor(ss, 1);
  ss += __shfl_xor(ss, 2);
  ss += __shfl_xor(ss, 4);
  const float sc = rsq(fmaxf(ss, 1e-24f));
  half8 hv;
  hv[0] = (_Float16)(v0.x * sc); hv[1] = (_Float16)(v0.y * sc);
  hv[2] = (_Float16)(v0.z * sc); hv[3] = (_Float16)(v0.w * sc);
  hv[4] = (_Float16)(v1.x * sc); hv[5] = (_Float16)(v1.y * sc);
  hv[6] = (_Float16)(v1.z * sc); hv[7] = (_Float16)(v1.w * sc);
  *(half8*)(tab + (size_t)row * 64 + part * 8) = hv;
}

// One block per (batch, pair). 256 threads = 4 waves.
// mm via mfma_f32_16x16x32_f16, swapped operands: D[doc][q], each lane's 4
// c-regs = 4 docs of ONE q-row. Compiler-codegen f32x2 exp-chain.
// LDS ~16.9 KB (ed chunk = 64 docs, 8 chunks): at VGPR=64 (launch_bounds
// (256,4) measured 64 in r9/r10 — (256,8) forced 32 + scratch spill, r11)
// all 8 blocks/CU can be co-resident: 8 x 16.9 KB = 135 KB < 160 KB.
template <bool PRENORM>
__global__ __launch_bounds__(256, 4) void knrm_main(
    const int* __restrict__ q1i, const int* __restrict__ d1i,
    const int* __restrict__ q2i, const int* __restrict__ d2i,
    const float* __restrict__ emb, const _Float16* __restrict__ tab,
    const float* __restrict__ w1, const float* __restrict__ b1,
    const float* __restrict__ w2, const float* __restrict__ b2,
    const float* __restrict__ w3, const float* __restrict__ b3,
    float* __restrict__ logits, int B)
{
  __shared__ _Float16 s_eq[64 * 64];
  __shared__ _Float16 s_ed[64 * 64];
  __shared__ float s_part[4][NK];
  __shared__ float s_F[NK];

  const int t = threadIdx.x;
  const int b = blockIdx.x;
  const int pair = blockIdx.y;
  const int* __restrict__ qid = pair ? q2i : q1i;
  const int* __restrict__ did = pair ? d2i : d1i;

  // exp(-0.5((x-mu)/sg)^2) = exp2(cf*(x-mu)^2), cf = -0.5*log2(e)/sg^2
  const float cf = -72.13475204444817f;   // sg = 0.1
  const float c1 = 7.213475204444817f;    // -2*cf*0.05
  // A[k] = exp(-0.5*(0.5+k)^2)
  const float A[10] = {
    0.88249690f, 0.32465247f, 0.043936934f, 0.0021874911f, 4.0065260e-5f,
    2.6995838e-7f, 6.6915900e-10f, 6.1022440e-13f, 2.0470720e-16f, 2.5261690e-20f};

  // ---------------- stage eq: 512 slots, 2 slot-writes/thread ----------
  // linear slot lin: row q = lin>>3, k-slot s = (lin&7)^(q&7);
  // swizzled addr(q,s) = q*8 + (s^(q&7)) = lin => write linear in t.
#pragma unroll
  for (int n = 0; n < 2; ++n) {
    const int lin = n * 256 + t;
    const int q = lin >> 3;
    const int s = (lin & 7) ^ (q & 7);
    const int id = qid[b * 64 + q];
    if (PRENORM) {
      *(half8*)&s_eq[lin * 8] = *(const half8*)(tab + (size_t)id * 64 + s * 8);
    } else {
      const float4* src = (const float4*)(emb + (size_t)id * 64 + s * 8);
      const float4 v0 = src[0], v1 = src[1];
      float ss = v0.x*v0.x + v0.y*v0.y + v0.z*v0.z + v0.w*v0.w
               + v1.x*v1.x + v1.y*v1.y + v1.z*v1.z + v1.w*v1.w;
      ss += __shfl_xor(ss, 1);
      ss += __shfl_xor(ss, 2);
      ss += __shfl_xor(ss, 4);
      const float sc = rsq(fmaxf(ss, 1e-24f));
      half8 hv;
      hv[0] = (_Float16)(v0.x * sc); hv[1] = (_Float16)(v0.y * sc);
      hv[2] = (_Float16)(v0.z * sc); hv[3] = (_Float16)(v0.w * sc);
      hv[4] = (_Float16)(v1.x * sc); hv[5] = (_Float16)(v1.y * sc);
      hv[6] = (_Float16)(v1.z * sc); hv[7] = (_Float16)(v1.w * sc);
      *(half8*)&s_eq[lin * 8] = hv;
    }
  }

  const int lane = t & 63;
  const int w  = t >> 6;             // wave id = q-tile
  const int lr = lane & 15;          // q index within tile
  const int lg = lane >> 4;          // k-group / doc-subgroup
  const int qrow = w * 16 + lr;

  f32x2 kacc2[20];
#pragma unroll
  for (int i = 0; i < 20; ++i) kacc2[i] = bc2(0.0f);
  float kacc20 = 0.0f;

  half8 af0, af1;                    // eq fragment (B operand), fixed per lane

  for (int ch = 0; ch < 8; ++ch) {   // 8 chunks of 64 docs
    if (ch) __syncthreads();         // prior chunk's mm reads done
    // -------------- stage ed chunk: 512 slots, 2 slot-writes/thread ----
#pragma unroll
    for (int n = 0; n < 2; ++n) {
      const int lin = n * 256 + t;
      const int d = lin >> 3;
      const int s = (lin & 7) ^ (d & 7);
      const int id = did[b * 512 + ch * 64 + d];
      if (PRENORM) {
        *(half8*)&s_ed[lin * 8] = *(const half8*)(tab + (size_t)id * 64 + s * 8);
      } else {
        const float4* src = (const float4*)(emb + (size_t)id * 64 + s * 8);
        const float4 v0 = src[0], v1 = src[1];
        float ss = v0.x*v0.x + v0.y*v0.y + v0.z*v0.z + v0.w*v0.w
                 + v1.x*v1.x + v1.y*v1.y + v1.z*v1.z + v1.w*v1.w;
        ss += __shfl_xor(ss, 1);
        ss += __shfl_xor(ss, 2);
        ss += __shfl_xor(ss, 4);
        const float sc = rsq(fmaxf(ss, 1e-24f));
        half8 hv;
        hv[0] = (_Float16)(v0.x * sc); hv[1] = (_Float16)(v0.y * sc);
        hv[2] = (_Float16)(v0.z * sc); hv[3] = (_Float16)(v0.w * sc);
        hv[4] = (_Float16)(v1.x * sc); hv[5] = (_Float16)(v1.y * sc);
        hv[6] = (_Float16)(v1.z * sc); hv[7] = (_Float16)(v1.w * sc);
        *(half8*)&s_ed[lin * 8] = hv;
      }
    }
    __syncthreads();

    if (ch == 0) {                    // B-fragments: load once, reuse
      const int q7 = qrow & 7;
      af0 = *(const half8*)&s_eq[(qrow * 8 + ((0 + lg) ^ q7)) * 8];
      af1 = *(const half8*)&s_eq[(qrow * 8 + ((4 + lg) ^ q7)) * 8];
    }

    // -------------- 4 d-tiles: 2 MFMA (A=ed) + packed exp-chain ---------
#pragma unroll
    for (int dt = 0; dt < 4; ++dt) {
      const int drow = dt * 16 + lr;
      const int d7 = drow & 7;
      const half8 b0 = *(const half8*)&s_ed[(drow * 8 + ((0 + lg) ^ d7)) * 8];
      const half8 b1 = *(const half8*)&s_ed[(drow * 8 + ((4 + lg) ^ d7)) * 8];
      floatx4 c = {0.0f, 0.0f, 0.0f, 0.0f};
      c = __builtin_amdgcn_mfma_f32_16x16x32_f16(b0, af0, c, 0, 0, 0);
      c = __builtin_amdgcn_mfma_f32_16x16x32_f16(b1, af1, c, 0, 0, 0);
      // c[r] = mm[doc = ch*64 + dt*16 + 4*lg + r][qrow]; 2 f32x2 pairs
#pragma unroll
      for (int pr = 0; pr < 2; ++pr) {
        const f32x2 x = {c[2 * pr], c[2 * pr + 1]};
        // mu=1.0, sg=0.001: nonzero only for exact token match (ref ~ 1.0)
        kacc20 += (x[0] > 0.99f ? 1.0f : 0.0f) + (x[1] > 0.99f ? 1.0f : 0.0f);
        const f32x2 xx = x * x;
        f32x2 u, gp, gn;
        u[0]  = ex2(cf * xx[0]); u[1]  = ex2(cf * xx[1]);
        const f32x2 ag = bc2(c1) * x;
        gp[0] = ex2(ag[0]);  gp[1] = ex2(ag[1]);
        gn[0] = ex2(-ag[0]); gn[1] = ex2(-ag[1]);
        const f32x2 h = gp * gp, rh = gn * gn;
        f32x2 v = u * gp, vn = u * gn;
#pragma unroll
        for (int k = 0; k < 10; ++k) {
          kacc2[10 + k] += v * bc2(A[k]);
          kacc2[9 - k]  += vn * bc2(A[k]);
          if (k < 9) { v *= h; vn *= rh; }
        }
      }
    }
  }

  // ---------------- reduce: docs (xor16,32) -> log1p -> q (xor1,2,4,8) ----
  float F[NK];
#pragma unroll
  for (int i = 0; i < NK; ++i) {
    float v = (i < 20) ? (kacc2[i][0] + kacc2[i][1]) : kacc20;
    v += __shfl_xor(v, 16);
    v += __shfl_xor(v, 32);                 // per-(q-row) total over 512 docs
    v = 0.6931471805599453f * lg2(1.0f + v);  // log1p
    v += __shfl_xor(v, 1);
    v += __shfl_xor(v, 2);
    v += __shfl_xor(v, 4);
    v += __shfl_xor(v, 8);                  // sum over this wave's 16 q-rows
    F[i] = v;
  }
  if (lane == 0) {
#pragma unroll
    for (int i = 0; i < NK; ++i) s_part[w][i] = F[i];
  }
  __syncthreads();

  if (t < NK)
    s_F[t] = s_part[0][t] + s_part[1][t] + s_part[2][t] + s_part[3][t];
  __syncthreads();

  // tiny MLP 21->10->5->1 on thread 0
  if (t == 0) {
    float h1[10], h2[5];
#pragma unroll
    for (int j = 0; j < 10; ++j) {
      float s = b1[j];
      for (int i = 0; i < NK; ++i) s = fmaf(s_F[i], w1[j * NK + i], s);
      h1[j] = fmaxf(s, 0.0f);
    }
#pragma unroll
    for (int j = 0; j < 5; ++j) {
      float s = b2[j];
#pragma unroll
      for (int i = 0; i < 10; ++i) s = fmaf(h1[i], w2[j * 10 + i], s);
      h2[j] = fmaxf(s, 0.0f);
    }
    float s = b3[0];
#pragma unroll
    for (int j = 0; j < 5; ++j) s = fmaf(h2[j], w3[j], s);
    logits[pair * B + b] = s;
  }
}

__global__ void knrm_finalize(const float* __restrict__ logits,
                              float* __restrict__ out, int B) {
  const int b = blockIdx.x * blockDim.x + threadIdx.x;
  if (b < B) {
    const float d = logits[b] - logits[B + b];
    out[b] = 1.0f / (1.0f + expf(-d));
  }
}

extern "C" void kernel_launch(void* const* d_in, const int* in_sizes, int n_in,
                              void* d_out, int out_size, void* d_ws, size_t ws_size,
                              hipStream_t stream) {
  const int* q1 = (const int*)d_in[0];
  const int* d1 = (const int*)d_in[1];
  const int* q2 = (const int*)d_in[2];
  const int* d2 = (const int*)d_in[3];
  const float* emb = (const float*)d_in[4];
  const float* w1 = (const float*)d_in[5];
  const float* b1 = (const float*)d_in[6];
  const float* w2 = (const float*)d_in[7];
  const float* b2 = (const float*)d_in[8];
  const float* w3 = (const float*)d_in[9];
  const float* b3 = (const float*)d_in[10];

  const int B = in_sizes[0] / 64;
  const int vocab = in_sizes[4] / 64;
  const size_t tab_bytes = (size_t)vocab * 64 * sizeof(_Float16);
  const bool prenorm = ws_size >= tab_bytes + (size_t)2 * B * sizeof(float) + 256;

  dim3 grid(B, 2);
  if (prenorm) {
    _Float16* tab = (_Float16*)d_ws;
    float* logits = (float*)((char*)d_ws + ((tab_bytes + 255) & ~(size_t)255));
    knrm_norm_table<<<(vocab + 31) / 32, 256, 0, stream>>>(emb, tab, vocab);
    knrm_main<true><<<grid, 256, 0, stream>>>(q1, d1, q2, d2, emb, tab,
                                              w1, b1, w2, b2, w3, b3, logits, B);
    knrm_finalize<<<(B + 255) / 256, 256, 0, stream>>>(logits, (float*)d_out, B);
  } else {
    float* logits = (float*)d_ws;
    knrm_main<false><<<grid, 256, 0, stream>>>(q1, d1, q2, d2, emb, nullptr,
                                               w1, b1, w2, b2, w3, b3, logits, B);
    knrm_finalize<<<(B + 255) / 256, 256, 0, stream>>>(logits, (float*)d_out, B);
  }
}

// Round 13
// 97.781 us; speedup vs baseline: 4.1572x; 2.4454x over previous
//
#include <hip/hip_runtime.h>
#include <math.h>

#define NK 21

typedef __attribute__((ext_vector_type(8))) _Float16 half8;
typedef __attribute__((ext_vector_type(4))) float floatx4;
typedef __attribute__((ext_vector_type(2))) float f32x2;

__device__ __forceinline__ float ex2(float x) { return __builtin_amdgcn_exp2f(x); }
__device__ __forceinline__ float rsq(float x) { return __builtin_amdgcn_rsqf(x); }
__device__ __forceinline__ float lg2(float x) { return __builtin_amdgcn_logf(x); }
__device__ __forceinline__ f32x2 bc2(float s) { f32x2 r = {s, s}; return r; }

// ---------------- normalized-f16 embedding table build ----------------
// 8 threads/row, 32 rows/block.
__global__ __launch_bounds__(256) void knrm_norm_table(
    const float* __restrict__ emb, _Float16* __restrict__ tab, int vocab) {
  const int t = threadIdx.x;
  const int row = blockIdx.x * 32 + (t >> 3);
  const int part = t & 7;
  if (row >= vocab) return;
  const float4* src = (const float4*)(emb + (size_t)row * 64 + part * 8);
  const float4 v0 = src[0], v1 = src[1];
  float ss = v0.x*v0.x + v0.y*v0.y + v0.z*v0.z + v0.w*v0.w
           + v1.x*v1.x + v1.y*v1.y + v1.z*v1.z + v1.w*v1.w;
  ss += __shfl_xor(ss, 1);
  ss += __shfl_xor(ss, 2);
  ss += __shfl_xor(ss, 4);
  const float sc = rsq(fmaxf(ss, 1e-24f));
  half8 hv;
  hv[0] = (_Float16)(v0.x * sc); hv[1] = (_Float16)(v0.y * sc);
  hv[2] = (_Float16)(v0.z * sc); hv[3] = (_Float16)(v0.w * sc);
  hv[4] = (_Float16)(v1.x * sc); hv[5] = (_Float16)(v1.y * sc);
  hv[6] = (_Float16)(v1.z * sc); hv[7] = (_Float16)(v1.w * sc);
  *(half8*)(tab + (size_t)row * 64 + part * 8) = hv;
}

// One block per (batch, pair). 256 threads = 4 waves.
// mm via mfma_f32_16x16x32_f16, swapped operands: D[doc][q], each lane's 4
// c-regs = 4 docs of ONE q-row. Compiler-codegen f32x2 exp-chain.
// LDS ~16.9 KB (ed chunk = 64 docs, 8 chunks) -> 8 blocks/CU possible at
// VGPR<=64.  CRITICAL: ch loop is `#pragma unroll 1` — full unroll of the
// constant-trip chunk loop let the scheduler hoist staging loads across
// chunk bodies, blowing live ranges -> scratch spill (r12: 401 MB
// WRITE_SIZE, 2.4x slowdown).
template <bool PRENORM>
__global__ __launch_bounds__(256, 4) void knrm_main(
    const int* __restrict__ q1i, const int* __restrict__ d1i,
    const int* __restrict__ q2i, const int* __restrict__ d2i,
    const float* __restrict__ emb, const _Float16* __restrict__ tab,
    const float* __restrict__ w1, const float* __restrict__ b1,
    const float* __restrict__ w2, const float* __restrict__ b2,
    const float* __restrict__ w3, const float* __restrict__ b3,
    float* __restrict__ logits, int B)
{
  __shared__ _Float16 s_eq[64 * 64];
  __shared__ _Float16 s_ed[64 * 64];
  __shared__ float s_part[4][NK];
  __shared__ float s_F[NK];

  const int t = threadIdx.x;
  const int b = blockIdx.x;
  const int pair = blockIdx.y;
  const int* __restrict__ qid = pair ? q2i : q1i;
  const int* __restrict__ did = pair ? d2i : d1i;

  // exp(-0.5((x-mu)/sg)^2) = exp2(cf*(x-mu)^2), cf = -0.5*log2(e)/sg^2
  const float cf = -72.13475204444817f;   // sg = 0.1
  const float c1 = 7.213475204444817f;    // -2*cf*0.05
  // A[k] = exp(-0.5*(0.5+k)^2)
  const float A[10] = {
    0.88249690f, 0.32465247f, 0.043936934f, 0.0021874911f, 4.0065260e-5f,
    2.6995838e-7f, 6.6915900e-10f, 6.1022440e-13f, 2.0470720e-16f, 2.5261690e-20f};

  // ---------------- stage eq: 512 slots, 2 slot-writes/thread ----------
  // linear slot lin: row q = lin>>3, k-slot s = (lin&7)^(q&7);
  // swizzled addr(q,s) = q*8 + (s^(q&7)) = lin => write linear in t.
#pragma unroll
  for (int n = 0; n < 2; ++n) {
    const int lin = n * 256 + t;
    const int q = lin >> 3;
    const int s = (lin & 7) ^ (q & 7);
    const int id = qid[b * 64 + q];
    if (PRENORM) {
      *(half8*)&s_eq[lin * 8] = *(const half8*)(tab + (size_t)id * 64 + s * 8);
    } else {
      const float4* src = (const float4*)(emb + (size_t)id * 64 + s * 8);
      const float4 v0 = src[0], v1 = src[1];
      float ss = v0.x*v0.x + v0.y*v0.y + v0.z*v0.z + v0.w*v0.w
               + v1.x*v1.x + v1.y*v1.y + v1.z*v1.z + v1.w*v1.w;
      ss += __shfl_xor(ss, 1);
      ss += __shfl_xor(ss, 2);
      ss += __shfl_xor(ss, 4);
      const float sc = rsq(fmaxf(ss, 1e-24f));
      half8 hv;
      hv[0] = (_Float16)(v0.x * sc); hv[1] = (_Float16)(v0.y * sc);
      hv[2] = (_Float16)(v0.z * sc); hv[3] = (_Float16)(v0.w * sc);
      hv[4] = (_Float16)(v1.x * sc); hv[5] = (_Float16)(v1.y * sc);
      hv[6] = (_Float16)(v1.z * sc); hv[7] = (_Float16)(v1.w * sc);
      *(half8*)&s_eq[lin * 8] = hv;
    }
  }

  const int lane = t & 63;
  const int w  = t >> 6;             // wave id = q-tile
  const int lr = lane & 15;          // q index within tile
  const int lg = lane >> 4;          // k-group / doc-subgroup
  const int qrow = w * 16 + lr;

  f32x2 kacc2[20];
#pragma unroll
  for (int i = 0; i < 20; ++i) kacc2[i] = bc2(0.0f);
  float kacc20 = 0.0f;

  half8 af0, af1;                    // eq fragment (B operand), fixed per lane

#pragma unroll 1                     // DO NOT unroll: see header comment
  for (int ch = 0; ch < 8; ++ch) {   // 8 chunks of 64 docs
    if (ch) __syncthreads();         // prior chunk's mm reads done
    // -------------- stage ed chunk: 512 slots, 2 slot-writes/thread ----
#pragma unroll
    for (int n = 0; n < 2; ++n) {
      const int lin = n * 256 + t;
      const int d = lin >> 3;
      const int s = (lin & 7) ^ (d & 7);
      const int id = did[b * 512 + ch * 64 + d];
      if (PRENORM) {
        *(half8*)&s_ed[lin * 8] = *(const half8*)(tab + (size_t)id * 64 + s * 8);
      } else {
        const float4* src = (const float4*)(emb + (size_t)id * 64 + s * 8);
        const float4 v0 = src[0], v1 = src[1];
        float ss = v0.x*v0.x + v0.y*v0.y + v0.z*v0.z + v0.w*v0.w
                 + v1.x*v1.x + v1.y*v1.y + v1.z*v1.z + v1.w*v1.w;
        ss += __shfl_xor(ss, 1);
        ss += __shfl_xor(ss, 2);
        ss += __shfl_xor(ss, 4);
        const float sc = rsq(fmaxf(ss, 1e-24f));
        half8 hv;
        hv[0] = (_Float16)(v0.x * sc); hv[1] = (_Float16)(v0.y * sc);
        hv[2] = (_Float16)(v0.z * sc); hv[3] = (_Float16)(v0.w * sc);
        hv[4] = (_Float16)(v1.x * sc); hv[5] = (_Float16)(v1.y * sc);
        hv[6] = (_Float16)(v1.z * sc); hv[7] = (_Float16)(v1.w * sc);
        *(half8*)&s_ed[lin * 8] = hv;
      }
    }
    __syncthreads();

    if (ch == 0) {                    // B-fragments: load once, reuse
      const int q7 = qrow & 7;
      af0 = *(const half8*)&s_eq[(qrow * 8 + ((0 + lg) ^ q7)) * 8];
      af1 = *(const half8*)&s_eq[(qrow * 8 + ((4 + lg) ^ q7)) * 8];
    }

    // -------------- 4 d-tiles: 2 MFMA (A=ed) + packed exp-chain ---------
#pragma unroll
    for (int dt = 0; dt < 4; ++dt) {
      const int drow = dt * 16 + lr;
      const int d7 = drow & 7;
      const half8 b0 = *(const half8*)&s_ed[(drow * 8 + ((0 + lg) ^ d7)) * 8];
      const half8 b1 = *(const half8*)&s_ed[(drow * 8 + ((4 + lg) ^ d7)) * 8];
      floatx4 c = {0.0f, 0.0f, 0.0f, 0.0f};
      c = __builtin_amdgcn_mfma_f32_16x16x32_f16(b0, af0, c, 0, 0, 0);
      c = __builtin_amdgcn_mfma_f32_16x16x32_f16(b1, af1, c, 0, 0, 0);
      // c[r] = mm[doc = ch*64 + dt*16 + 4*lg + r][qrow]; 2 f32x2 pairs
#pragma unroll
      for (int pr = 0; pr < 2; ++pr) {
        const f32x2 x = {c[2 * pr], c[2 * pr + 1]};
        // mu=1.0, sg=0.001: nonzero only for exact token match (ref ~ 1.0)
        kacc20 += (x[0] > 0.99f ? 1.0f : 0.0f) + (x[1] > 0.99f ? 1.0f : 0.0f);
        const f32x2 xx = x * x;
        f32x2 u, gp, gn;
        u[0]  = ex2(cf * xx[0]); u[1]  = ex2(cf * xx[1]);
        const f32x2 ag = bc2(c1) * x;
        gp[0] = ex2(ag[0]);  gp[1] = ex2(ag[1]);
        gn[0] = ex2(-ag[0]); gn[1] = ex2(-ag[1]);
        const f32x2 h = gp * gp, rh = gn * gn;
        f32x2 v = u * gp, vn = u * gn;
#pragma unroll
        for (int k = 0; k < 10; ++k) {
          kacc2[10 + k] += v * bc2(A[k]);
          kacc2[9 - k]  += vn * bc2(A[k]);
          if (k < 9) { v *= h; vn *= rh; }
        }
      }
    }
  }

  // ---------------- reduce: docs (xor16,32) -> log1p -> q (xor1,2,4,8) ----
  float F[NK];
#pragma unroll
  for (int i = 0; i < NK; ++i) {
    float v = (i < 20) ? (kacc2[i][0] + kacc2[i][1]) : kacc20;
    v += __shfl_xor(v, 16);
    v += __shfl_xor(v, 32);                 // per-(q-row) total over 512 docs
    v = 0.6931471805599453f * lg2(1.0f + v);  // log1p
    v += __shfl_xor(v, 1);
    v += __shfl_xor(v, 2);
    v += __shfl_xor(v, 4);
    v += __shfl_xor(v, 8);                  // sum over this wave's 16 q-rows
    F[i] = v;
  }
  if (lane == 0) {
#pragma unroll
    for (int i = 0; i < NK; ++i) s_part[w][i] = F[i];
  }
  __syncthreads();

  if (t < NK)
    s_F[t] = s_part[0][t] + s_part[1][t] + s_part[2][t] + s_part[3][t];
  __syncthreads();

  // tiny MLP 21->10->5->1 on thread 0
  if (t == 0) {
    float h1[10], h2[5];
#pragma unroll
    for (int j = 0; j < 10; ++j) {
      float s = b1[j];
      for (int i = 0; i < NK; ++i) s = fmaf(s_F[i], w1[j * NK + i], s);
      h1[j] = fmaxf(s, 0.0f);
    }
#pragma unroll
    for (int j = 0; j < 5; ++j) {
      float s = b2[j];
#pragma unroll
      for (int i = 0; i < 10; ++i) s = fmaf(h1[i], w2[j * 10 + i], s);
      h2[j] = fmaxf(s, 0.0f);
    }
    float s = b3[0];
#pragma unroll
    for (int j = 0; j < 5; ++j) s = fmaf(h2[j], w3[j], s);
    logits[pair * B + b] = s;
  }
}

__global__ void knrm_finalize(const float* __restrict__ logits,
                              float* __restrict__ out, int B) {
  const int b = blockIdx.x * blockDim.x + threadIdx.x;
  if (b < B) {
    const float d = logits[b] - logits[B + b];
    out[b] = 1.0f / (1.0f + expf(-d));
  }
}

extern "C" void kernel_launch(void* const* d_in, const int* in_sizes, int n_in,
                              void* d_out, int out_size, void* d_ws, size_t ws_size,
                              hipStream_t stream) {
  const int* q1 = (const int*)d_in[0];
  const int* d1 = (const int*)d_in[1];
  const int* q2 = (const int*)d_in[2];
  const int* d2 = (const int*)d_in[3];
  const float* emb = (const float*)d_in[4];
  const float* w1 = (const float*)d_in[5];
  const float* b1 = (const float*)d_in[6];
  const float* w2 = (const float*)d_in[7];
  const float* b2 = (const float*)d_in[8];
  const float* w3 = (const float*)d_in[9];
  const float* b3 = (const float*)d_in[10];

  const int B = in_sizes[0] / 64;
  const int vocab = in_sizes[4] / 64;
  const size_t tab_bytes = (size_t)vocab * 64 * sizeof(_Float16);
  const bool prenorm = ws_size >= tab_bytes + (size_t)2 * B * sizeof(float) + 256;

  dim3 grid(B, 2);
  if (prenorm) {
    _Float16* tab = (_Float16*)d_ws;
    float* logits = (float*)((char*)d_ws + ((tab_bytes + 255) & ~(size_t)255));
    knrm_norm_table<<<(vocab + 31) / 32, 256, 0, stream>>>(emb, tab, vocab);
    knrm_main<true><<<grid, 256, 0, stream>>>(q1, d1, q2, d2, emb, tab,
                                              w1, b1, w2, b2, w3, b3, logits, B);
    knrm_finalize<<<(B + 255) / 256, 256, 0, stream>>>(logits, (float*)d_out, B);
  } else {
    float* logits = (float*)d_ws;
    knrm_main<false><<<grid, 256, 0, stream>>>(q1, d1, q2, d2, emb, nullptr,
                                               w1, b1, w2, b2, w3, b3, logits, B);
    knrm_finalize<<<(B + 255) / 256, 256, 0, stream>>>(logits, (float*)d_out, B);
  }
}

// Round 14
// 97.668 us; speedup vs baseline: 4.1620x; 1.0012x over previous
//
#include <hip/hip_runtime.h>
#include <math.h>

#define NK 21

typedef __attribute__((ext_vector_type(8))) _Float16 half8;
typedef __attribute__((ext_vector_type(4))) float floatx4;
typedef __attribute__((ext_vector_type(2))) float f32x2;

__device__ __forceinline__ float ex2(float x) { return __builtin_amdgcn_exp2f(x); }
__device__ __forceinline__ float rsq(float x) { return __builtin_amdgcn_rsqf(x); }
__device__ __forceinline__ float lg2(float x) { return __builtin_amdgcn_logf(x); }
__device__ __forceinline__ f32x2 bc2(float s) { f32x2 r = {s, s}; return r; }

// ---------------- normalized-f16 embedding table build ----------------
__global__ __launch_bounds__(256) void knrm_norm_table(
    const float* __restrict__ emb, _Float16* __restrict__ tab, int vocab) {
  const int t = threadIdx.x;
  const int row = blockIdx.x * 32 + (t >> 3);
  const int part = t & 7;
  if (row >= vocab) return;
  const float4* src = (const float4*)(emb + (size_t)row * 64 + part * 8);
  const float4 v0 = src[0], v1 = src[1];
  float ss = v0.x*v0.x + v0.y*v0.y + v0.z*v0.z + v0.w*v0.w
           + v1.x*v1.x + v1.y*v1.y + v1.z*v1.z + v1.w*v1.w;
  ss += __shfl_xor(ss, 1);
  ss += __shfl_xor(ss, 2);
  ss += __shfl_xor(ss, 4);
  const float sc = rsq(fmaxf(ss, 1e-24f));
  half8 hv;
  hv[0] = (_Float16)(v0.x * sc); hv[1] = (_Float16)(v0.y * sc);
  hv[2] = (_Float16)(v0.z * sc); hv[3] = (_Float16)(v0.w * sc);
  hv[4] = (_Float16)(v1.x * sc); hv[5] = (_Float16)(v1.y * sc);
  hv[6] = (_Float16)(v1.z * sc); hv[7] = (_Float16)(v1.w * sc);
  *(half8*)(tab + (size_t)row * 64 + part * 8) = hv;
}

// One block per (batch, pair), FLAT 1-D grid (pair = bid&1) — tests the
// grid.y dispatch-serialization hypothesis. 256 threads = 4 waves.
// mm via mfma_f32_16x16x32_f16, swapped operands: D[doc][q].
// T14 async-stage: next chunk's table rows are gathered into REGISTERS
// during the current chunk's compute (compute phase has no VMEM, so the
// loads stay in flight across the barrier); ds_write at loop top.
// ch loop is `#pragma unroll 1` (r12: full unroll -> 401 MB spill).
template <bool PRENORM>
__global__ __launch_bounds__(256, 4) void knrm_main(
    const int* __restrict__ q1i, const int* __restrict__ d1i,
    const int* __restrict__ q2i, const int* __restrict__ d2i,
    const float* __restrict__ emb, const _Float16* __restrict__ tab,
    const float* __restrict__ w1, const float* __restrict__ b1,
    const float* __restrict__ w2, const float* __restrict__ b2,
    const float* __restrict__ w3, const float* __restrict__ b3,
    float* __restrict__ logits, int B)
{
  __shared__ _Float16 s_eq[64 * 64];
  __shared__ _Float16 s_ed[64 * 64];
  __shared__ float s_part[4][NK];
  __shared__ float s_F[NK];

  const int t = threadIdx.x;
  const int bid = blockIdx.x;
  const int b = bid >> 1;
  const int pair = bid & 1;
  const int* __restrict__ qid = pair ? q2i : q1i;
  const int* __restrict__ did = pair ? d2i : d1i;

  // exp(-0.5((x-mu)/sg)^2) = exp2(cf*(x-mu)^2), cf = -0.5*log2(e)/sg^2
  const float cf = -72.13475204444817f;   // sg = 0.1
  const float c1 = 7.213475204444817f;    // -2*cf*0.05
  // A[k] = exp(-0.5*(0.5+k)^2)
  const float A[10] = {
    0.88249690f, 0.32465247f, 0.043936934f, 0.0021874911f, 4.0065260e-5f,
    2.6995838e-7f, 6.6915900e-10f, 6.1022440e-13f, 2.0470720e-16f, 2.5261690e-20f};

  // ---------------- stage eq: 512 slots, 2 slot-writes/thread ----------
#pragma unroll
  for (int n = 0; n < 2; ++n) {
    const int lin = n * 256 + t;
    const int q = lin >> 3;
    const int s = (lin & 7) ^ (q & 7);
    const int id = qid[b * 64 + q];
    if (PRENORM) {
      *(half8*)&s_eq[lin * 8] = *(const half8*)(tab + (size_t)id * 64 + s * 8);
    } else {
      const float4* src = (const float4*)(emb + (size_t)id * 64 + s * 8);
      const float4 v0 = src[0], v1 = src[1];
      float ss = v0.x*v0.x + v0.y*v0.y + v0.z*v0.z + v0.w*v0.w
               + v1.x*v1.x + v1.y*v1.y + v1.z*v1.z + v1.w*v1.w;
      ss += __shfl_xor(ss, 1);
      ss += __shfl_xor(ss, 2);
      ss += __shfl_xor(ss, 4);
      const float sc = rsq(fmaxf(ss, 1e-24f));
      half8 hv;
      hv[0] = (_Float16)(v0.x * sc); hv[1] = (_Float16)(v0.y * sc);
      hv[2] = (_Float16)(v0.z * sc); hv[3] = (_Float16)(v0.w * sc);
      hv[4] = (_Float16)(v1.x * sc); hv[5] = (_Float16)(v1.y * sc);
      hv[6] = (_Float16)(v1.z * sc); hv[7] = (_Float16)(v1.w * sc);
      *(half8*)&s_eq[lin * 8] = hv;
    }
  }

  const int lane = t & 63;
  const int w  = t >> 6;             // wave id = q-tile
  const int lr = lane & 15;          // q index within tile
  const int lg = lane >> 4;          // k-group / doc-subgroup
  const int qrow = w * 16 + lr;

  f32x2 kacc2[20];
#pragma unroll
  for (int i = 0; i < 20; ++i) kacc2[i] = bc2(0.0f);
  float kacc20 = 0.0f;

  half8 af0, af1;                    // eq fragment (B operand), fixed per lane

  // per-thread staging geometry (static per thread)
  const int d0s = t >> 3;                       // lin0 = t
  const int s0s = (t & 7) ^ (d0s & 7);
  const int d1s = (256 + t) >> 3;               // lin1 = 256 + t
  const int s1s = ((256 + t) & 7) ^ (d1s & 7);

  half8 pf0, pf1;                    // prefetched rows (PRENORM path)
  if (PRENORM) {
    const int id0 = did[b * 512 + d0s];
    const int id1 = did[b * 512 + d1s];
    pf0 = *(const half8*)(tab + (size_t)id0 * 64 + s0s * 8);
    pf1 = *(const half8*)(tab + (size_t)id1 * 64 + s1s * 8);
  }

#pragma unroll 1                     // DO NOT unroll (r12 spill lesson)
  for (int ch = 0; ch < 8; ++ch) {   // 8 chunks of 64 docs
    if (ch) __syncthreads();         // prior chunk's mm reads done
    if (PRENORM) {
      // write prefetched rows (implicit vmcnt wait), then issue next gather
      *(half8*)&s_ed[t * 8] = pf0;
      *(half8*)&s_ed[(256 + t) * 8] = pf1;
      if (ch < 7) {
        const int id0 = did[b * 512 + (ch + 1) * 64 + d0s];
        const int id1 = did[b * 512 + (ch + 1) * 64 + d1s];
        pf0 = *(const half8*)(tab + (size_t)id0 * 64 + s0s * 8);
        pf1 = *(const half8*)(tab + (size_t)id1 * 64 + s1s * 8);
      }
    } else {
#pragma unroll
      for (int n = 0; n < 2; ++n) {
        const int lin = n * 256 + t;
        const int d = lin >> 3;
        const int s = (lin & 7) ^ (d & 7);
        const int id = did[b * 512 + ch * 64 + d];
        const float4* src = (const float4*)(emb + (size_t)id * 64 + s * 8);
        const float4 v0 = src[0], v1 = src[1];
        float ss = v0.x*v0.x + v0.y*v0.y + v0.z*v0.z + v0.w*v0.w
                 + v1.x*v1.x + v1.y*v1.y + v1.z*v1.z + v1.w*v1.w;
        ss += __shfl_xor(ss, 1);
        ss += __shfl_xor(ss, 2);
        ss += __shfl_xor(ss, 4);
        const float sc = rsq(fmaxf(ss, 1e-24f));
        half8 hv;
        hv[0] = (_Float16)(v0.x * sc); hv[1] = (_Float16)(v0.y * sc);
        hv[2] = (_Float16)(v0.z * sc); hv[3] = (_Float16)(v0.w * sc);
        hv[4] = (_Float16)(v1.x * sc); hv[5] = (_Float16)(v1.y * sc);
        hv[6] = (_Float16)(v1.z * sc); hv[7] = (_Float16)(v1.w * sc);
        *(half8*)&s_ed[lin * 8] = hv;
      }
    }
    __syncthreads();

    if (ch == 0) {                    // B-fragments: load once, reuse
      const int q7 = qrow & 7;
      af0 = *(const half8*)&s_eq[(qrow * 8 + ((0 + lg) ^ q7)) * 8];
      af1 = *(const half8*)&s_eq[(qrow * 8 + ((4 + lg) ^ q7)) * 8];
    }

    // -------------- 4 d-tiles: 2 MFMA (A=ed) + packed exp-chain ---------
#pragma unroll
    for (int dt = 0; dt < 4; ++dt) {
      const int drow = dt * 16 + lr;
      const int d7 = drow & 7;
      const half8 b0 = *(const half8*)&s_ed[(drow * 8 + ((0 + lg) ^ d7)) * 8];
      const half8 b1 = *(const half8*)&s_ed[(drow * 8 + ((4 + lg) ^ d7)) * 8];
      floatx4 c = {0.0f, 0.0f, 0.0f, 0.0f};
      c = __builtin_amdgcn_mfma_f32_16x16x32_f16(b0, af0, c, 0, 0, 0);
      c = __builtin_amdgcn_mfma_f32_16x16x32_f16(b1, af1, c, 0, 0, 0);
      // c[r] = mm[doc = ch*64 + dt*16 + 4*lg + r][qrow]; 2 f32x2 pairs
#pragma unroll
      for (int pr = 0; pr < 2; ++pr) {
        const f32x2 x = {c[2 * pr], c[2 * pr + 1]};
        // mu=1.0, sg=0.001: nonzero only for exact token match (ref ~ 1.0)
        kacc20 += (x[0] > 0.99f ? 1.0f : 0.0f) + (x[1] > 0.99f ? 1.0f : 0.0f);
        const f32x2 xx = x * x;
        f32x2 u, gp, gn;
        u[0]  = ex2(cf * xx[0]); u[1]  = ex2(cf * xx[1]);
        const f32x2 ag = bc2(c1) * x;
        gp[0] = ex2(ag[0]);  gp[1] = ex2(ag[1]);
        gn[0] = ex2(-ag[0]); gn[1] = ex2(-ag[1]);
        const f32x2 h = gp * gp, rh = gn * gn;
        f32x2 v = u * gp, vn = u * gn;
#pragma unroll
        for (int k = 0; k < 10; ++k) {
          kacc2[10 + k] += v * bc2(A[k]);
          kacc2[9 - k]  += vn * bc2(A[k]);
          if (k < 9) { v *= h; vn *= rh; }
        }
      }
    }
  }

  // ---------------- reduce: docs (xor16,32) -> log1p -> q (xor1,2,4,8) ----
  float F[NK];
#pragma unroll
  for (int i = 0; i < NK; ++i) {
    float v = (i < 20) ? (kacc2[i][0] + kacc2[i][1]) : kacc20;
    v += __shfl_xor(v, 16);
    v += __shfl_xor(v, 32);                 // per-(q-row) total over 512 docs
    v = 0.6931471805599453f * lg2(1.0f + v);  // log1p
    v += __shfl_xor(v, 1);
    v += __shfl_xor(v, 2);
    v += __shfl_xor(v, 4);
    v += __shfl_xor(v, 8);                  // sum over this wave's 16 q-rows
    F[i] = v;
  }
  if (lane == 0) {
#pragma unroll
    for (int i = 0; i < NK; ++i) s_part[w][i] = F[i];
  }
  __syncthreads();

  if (t < NK)
    s_F[t] = s_part[0][t] + s_part[1][t] + s_part[2][t] + s_part[3][t];
  __syncthreads();

  // tiny MLP 21->10->5->1 on thread 0
  if (t == 0) {
    float h1[10], h2[5];
#pragma unroll
    for (int j = 0; j < 10; ++j) {
      float s = b1[j];
      for (int i = 0; i < NK; ++i) s = fmaf(s_F[i], w1[j * NK + i], s);
      h1[j] = fmaxf(s, 0.0f);
    }
#pragma unroll
    for (int j = 0; j < 5; ++j) {
      float s = b2[j];
#pragma unroll
      for (int i = 0; i < 10; ++i) s = fmaf(h1[i], w2[j * 10 + i], s);
      h2[j] = fmaxf(s, 0.0f);
    }
    float s = b3[0];
#pragma unroll
    for (int j = 0; j < 5; ++j) s = fmaf(h2[j], w3[j], s);
    logits[pair * B + b] = s;
  }
}

__global__ void knrm_finalize(const float* __restrict__ logits,
                              float* __restrict__ out, int B) {
  const int b = blockIdx.x * blockDim.x + threadIdx.x;
  if (b < B) {
    const float d = logits[b] - logits[B + b];
    out[b] = 1.0f / (1.0f + expf(-d));
  }
}

extern "C" void kernel_launch(void* const* d_in, const int* in_sizes, int n_in,
                              void* d_out, int out_size, void* d_ws, size_t ws_size,
                              hipStream_t stream) {
  const int* q1 = (const int*)d_in[0];
  const int* d1 = (const int*)d_in[1];
  const int* q2 = (const int*)d_in[2];
  const int* d2 = (const int*)d_in[3];
  const float* emb = (const float*)d_in[4];
  const float* w1 = (const float*)d_in[5];
  const float* b1 = (const float*)d_in[6];
  const float* w2 = (const float*)d_in[7];
  const float* b2 = (const float*)d_in[8];
  const float* w3 = (const float*)d_in[9];
  const float* b3 = (const float*)d_in[10];

  const int B = in_sizes[0] / 64;
  const int vocab = in_sizes[4] / 64;
  const size_t tab_bytes = (size_t)vocab * 64 * sizeof(_Float16);
  const bool prenorm = ws_size >= tab_bytes + (size_t)2 * B * sizeof(float) + 256;

  if (prenorm) {
    _Float16* tab = (_Float16*)d_ws;
    float* logits = (float*)((char*)d_ws + ((tab_bytes + 255) & ~(size_t)255));
    knrm_norm_table<<<(vocab + 31) / 32, 256, 0, stream>>>(emb, tab, vocab);
    knrm_main<true><<<2 * B, 256, 0, stream>>>(q1, d1, q2, d2, emb, tab,
                                               w1, b1, w2, b2, w3, b3, logits, B);
    knrm_finalize<<<(B + 255) / 256, 256, 0, stream>>>(logits, (float*)d_out, B);
  } else {
    float* logits = (float*)d_ws;
    knrm_main<false><<<2 * B, 256, 0, stream>>>(q1, d1, q2, d2, emb, nullptr,
                                                w1, b1, w2, b2, w3, b3, logits, B);
    knrm_finalize<<<(B + 255) / 256, 256, 0, stream>>>(logits, (float*)d_out, B);
  }
}